// Round 11
// baseline (350.902 us; speedup 1.0000x reference)
//
#include <hip/hip_runtime.h>
#include <hip/hip_bf16.h>
#include <math.h>

#define NEG_SLOPE 0.2f

__device__ __forceinline__ float lrelu(float x){ return x > 0.f ? x : NEG_SLOPE * x; }
__device__ __forceinline__ unsigned short f2bf(float f){
  __hip_bfloat16 h = __float2bfloat16(f);
  return __builtin_bit_cast(unsigned short, h);
}
__device__ __forceinline__ float b2f(unsigned u){
  return __builtin_bit_cast(float, u << 16);
}
__device__ __forceinline__ float b2fh(unsigned u){
  return __builtin_bit_cast(float, u & 0xffff0000u);
}

typedef short bf16x8 __attribute__((ext_vector_type(8)));
typedef float f32x4 __attribute__((ext_vector_type(4)));

// ---------------- CSR build + weight transpose (merged) ----------------
__global__ void k_count_wt(const int* __restrict__ dst, int* __restrict__ deg, int E, int eb,
                           const float* __restrict__ W1, unsigned short* __restrict__ W1t,
                           const float* __restrict__ W2, unsigned short* __restrict__ W2t){
  int b = blockIdx.x, tid = threadIdx.x;
  if (b < eb){
    int e = b*256 + tid;
    if (e < E) atomicAdd(&deg[dst[e]], 1);
  } else {
    int bb = b - eb;
    if (bb < 128){                    // W1: 256 cols, K=128; 2 cols per block
      int c = bb*2 + (tid>>7), k = tid & 127;
      W1t[(size_t)c*128 + k] = f2bf(W1[(size_t)k*256 + c]);
    } else {                          // W2: 64 cols (pad>=40 -> 0), K=256
      int c = bb - 128, k = tid;
      float v = (c < 40) ? W2[(size_t)k*40 + c] : 0.f;
      W2t[(size_t)c*256 + k] = f2bf(v);
    }
  }
}

__global__ __launch_bounds__(256) void k_scan1(const int* __restrict__ deg, int* __restrict__ bsum, int n){
  int tid = threadIdx.x;
  int base = blockIdx.x*1024 + tid*4;
  int s = 0;
  #pragma unroll
  for (int j=0;j<4;j++){ int idx = base+j; if (idx < n) s += deg[idx]; }
  #pragma unroll
  for (int off=32; off; off>>=1) s += __shfl_xor(s, off);
  __shared__ int ws[4];
  if ((tid&63)==0) ws[tid>>6] = s;
  __syncthreads();
  if (tid==0) bsum[blockIdx.x] = ws[0]+ws[1]+ws[2]+ws[3];
}

// local scan + inline block-offset scan (nb <= 64)
__global__ __launch_bounds__(256) void k_scan3(const int* __restrict__ deg, const int* __restrict__ bsum,
    int* __restrict__ rowptr, int* __restrict__ nxt, int n, int nb){
  int tid = threadIdx.x; int lane = tid & 63, w = tid >> 6;
  __shared__ int ws[4];
  __shared__ int s_boff;
  if (tid < 64){
    int v = (lane < nb) ? bsum[lane] : 0;
    int inc = v;
    #pragma unroll
    for (int off=1; off<64; off<<=1){ int t = __shfl_up(inc, off); if (lane >= off) inc += t; }
    if (lane == blockIdx.x) s_boff = inc - v;
    if (blockIdx.x == 0 && lane == nb-1) rowptr[n] = inc;
  }
  __syncthreads();
  int base = blockIdx.x*1024 + tid*4;
  int v[4]; int s = 0;
  #pragma unroll
  for (int j=0;j<4;j++){ int idx = base+j; v[j] = (idx < n) ? deg[idx] : 0; s += v[j]; }
  int inc = s;
  #pragma unroll
  for (int off=1; off<64; off<<=1){ int t = __shfl_up(inc, off); if (lane >= off) inc += t; }
  if (lane == 63) ws[w] = inc;
  __syncthreads();
  int run = s_boff;
  for (int ww=0; ww<w; ww++) run += ws[ww];
  run += inc - s;
  #pragma unroll
  for (int j=0;j<4;j++){ int idx = base+j; if (idx < n){ rowptr[idx] = run; nxt[idx] = run; run += v[j]; } }
}

__global__ void k_scatter(const int* __restrict__ src, const int* __restrict__ dst,
                          int* __restrict__ nxt, int* __restrict__ srcs, int E){
  int e = blockIdx.x*256 + threadIdx.x;
  if (e < E){
    int pos = atomicAdd(&nxt[dst[e]], 1);
    srcs[pos] = src[e];
  }
}

// ---------------- edge p precompute (per-node waves; dst implicit) ----------------
__global__ __launch_bounds__(256) void k_edgep1n(const int* __restrict__ rowptr,
    const int* __restrict__ srcs, const float* __restrict__ asrc,
    const float* __restrict__ adst, unsigned short* __restrict__ p1, int n){
  int i = (blockIdx.x*256 + threadIdx.x) >> 6;
  int lane = threadIdx.x & 63;
  if (i >= n) return;
  int hd = lane & 7, eoff = lane >> 3;
  float ad = adst[(size_t)i*8 + hd];
  int e0 = rowptr[i], e1 = rowptr[i+1];
  for (int e = e0 + eoff; e < e1; e += 8){
    int s = srcs[e];
    p1[(size_t)e*8 + hd] = f2bf(__expf(lrelu(asrc[(size_t)s*8 + hd] + ad)));
  }
}

__global__ __launch_bounds__(256) void k_edgep2n(const int* __restrict__ rowptr,
    const int* __restrict__ srcs, const float* __restrict__ asrc,
    const float* __restrict__ adst, float* __restrict__ p2, int n){
  int i = (blockIdx.x*256 + threadIdx.x) >> 6;
  int lane = threadIdx.x & 63;
  if (i >= n) return;
  float ad = adst[i];
  int e0 = rowptr[i], e1 = rowptr[i+1];
  for (int e = e0 + lane; e < e1; e += 64){
    p2[e] = __expf(lrelu(asrc[srcs[e]] + ad));
  }
}

// ---------------- layer-1 GEMM (fp32 A staged->bf16) + fused attention dots ------
__global__ __launch_bounds__(256) void gemm1_att(
    const float* __restrict__ x, const unsigned short* __restrict__ Bt,
    unsigned short* __restrict__ C, const float* __restrict__ att_s,
    const float* __restrict__ att_d, float* __restrict__ asrc,
    float* __restrict__ adst, int M){
  __shared__ unsigned short sA[64][40];
  __shared__ unsigned short sB[256][40];
  const int tid = threadIdx.x;
  const int wid = tid >> 6, lane = tid & 63;
  const int r0 = blockIdx.x * 64;
  const int fr = lane & 15, fk = (lane >> 4) * 8;
  f32x4 acc[4][4] = {};

  for (int k0 = 0; k0 < 128; k0 += 32){
    #pragma unroll
    for (int t=0; t<2; t++){
      int id = tid + t*256;          // 0..511
      int r = id >> 3, q = id & 7;   // row, k-quad
      float4 v = make_float4(0.f,0.f,0.f,0.f);
      int row = r0 + r;
      if (row < M) v = ((const float4*)(x + (size_t)row*128))[(k0>>2) + q];
      ushort4 o; o.x=f2bf(v.x); o.y=f2bf(v.y); o.z=f2bf(v.z); o.w=f2bf(v.w);
      *(ushort4*)&sA[r][q*4] = o;
    }
    #pragma unroll
    for (int t=0; t<4; t++){
      int id = tid + t*256;          // 0..1023
      int r = id >> 2, lk = (id & 3) * 8;
      uint4 vb = *(const uint4*)(Bt + (size_t)r*128 + k0 + lk);
      *(uint4*)&sB[r][lk] = vb;
    }
    __syncthreads();
    bf16x8 a[4], b[4];
    #pragma unroll
    for (int mi=0; mi<4; mi++) a[mi] = *(const bf16x8*)&sA[mi*16 + fr][fk];
    #pragma unroll
    for (int ni=0; ni<4; ni++) b[ni] = *(const bf16x8*)&sB[wid*64 + ni*16 + fr][fk];
    #pragma unroll
    for (int mi=0; mi<4; mi++)
      #pragma unroll
      for (int ni=0; ni<4; ni++)
        acc[mi][ni] = __builtin_amdgcn_mfma_f32_16x16x32_bf16(a[mi], b[ni], acc[mi][ni], 0,0,0);
    __syncthreads();
  }

  float avs[4], avd[4];
  #pragma unroll
  for (int ni=0; ni<4; ni++){
    int idx = (2*wid + (ni>>1))*32 + (ni&1)*16 + fr;
    avs[ni] = att_s[idx];
    avd[ni] = att_d[idx];
  }

  #pragma unroll
  for (int mi=0; mi<4; mi++){
    #pragma unroll
    for (int j=0; j<4; j++){
      int row = r0 + mi*16 + (lane>>4)*4 + j;
      #pragma unroll
      for (int ni=0; ni<4; ni++){
        int col = wid*64 + ni*16 + fr;
        if (row < M) C[(size_t)row*256 + col] = f2bf(acc[mi][ni][j]);
      }
      float s0 = acc[mi][0][j]*avs[0] + acc[mi][1][j]*avs[1];
      float s1 = acc[mi][2][j]*avs[2] + acc[mi][3][j]*avs[3];
      float d0 = acc[mi][0][j]*avd[0] + acc[mi][1][j]*avd[1];
      float d1 = acc[mi][2][j]*avd[2] + acc[mi][3][j]*avd[3];
      #pragma unroll
      for (int mk=1; mk<16; mk<<=1){
        s0 += __shfl_xor(s0, mk); s1 += __shfl_xor(s1, mk);
        d0 += __shfl_xor(d0, mk); d1 += __shfl_xor(d1, mk);
      }
      if ((lane & 15) == 0 && row < M){
        asrc[(size_t)row*8 + 2*wid    ] = s0;
        asrc[(size_t)row*8 + 2*wid + 1] = s1;
        adst[(size_t)row*8 + 2*wid    ] = d0;
        adst[(size_t)row*8 + 2*wid + 1] = d1;
      }
    }
  }
}

// ---------------- layer-2 GEMM + fused attention dots ----------------
__global__ __launch_bounds__(256) void gemm2_att(
    const unsigned short* __restrict__ A, const unsigned short* __restrict__ Bt,
    unsigned short* __restrict__ C, const float* __restrict__ att_s,
    const float* __restrict__ att_d, float* __restrict__ asrc,
    float* __restrict__ adst, int M){
  __shared__ unsigned short sA[64][40];
  __shared__ unsigned short sB[64][40];
  __shared__ float sS[2][64], sD[2][64];
  const int tid = threadIdx.x;
  const int wid = tid >> 6, lane = tid & 63;
  const int r0 = blockIdx.x * 64;
  const int wr = wid >> 1, wc = wid & 1;
  const int lr = tid >> 2;
  const int lk = (tid & 3) * 8;
  const int fr = lane & 15, fk = (lane >> 4) * 8;
  const int K = 256;
  f32x4 acc[2][2] = {};

  for (int k0 = 0; k0 < K; k0 += 32){
    uint4 va = make_uint4(0,0,0,0);
    int row = r0 + lr;
    if (row < M) va = *(const uint4*)(A + (size_t)row*K + k0 + lk);
    *(uint4*)&sA[lr][lk] = va;
    uint4 vb = *(const uint4*)(Bt + (size_t)lr*K + k0 + lk);
    *(uint4*)&sB[lr][lk] = vb;
    __syncthreads();
    bf16x8 a0 = *(const bf16x8*)&sA[wr*32 + fr][fk];
    bf16x8 a1 = *(const bf16x8*)&sA[wr*32 + 16 + fr][fk];
    bf16x8 b0 = *(const bf16x8*)&sB[wc*32 + fr][fk];
    bf16x8 b1 = *(const bf16x8*)&sB[wc*32 + 16 + fr][fk];
    acc[0][0] = __builtin_amdgcn_mfma_f32_16x16x32_bf16(a0, b0, acc[0][0], 0,0,0);
    acc[0][1] = __builtin_amdgcn_mfma_f32_16x16x32_bf16(a0, b1, acc[0][1], 0,0,0);
    acc[1][0] = __builtin_amdgcn_mfma_f32_16x16x32_bf16(a1, b0, acc[1][0], 0,0,0);
    acc[1][1] = __builtin_amdgcn_mfma_f32_16x16x32_bf16(a1, b1, acc[1][1], 0,0,0);
    __syncthreads();
  }

  float avs[2], avd[2];
  #pragma unroll
  for (int ni=0; ni<2; ni++){
    int col = wc*32 + ni*16 + fr;
    avs[ni] = (col < 40) ? att_s[col] : 0.f;
    avd[ni] = (col < 40) ? att_d[col] : 0.f;
  }

  #pragma unroll
  for (int mi=0; mi<2; mi++){
    #pragma unroll
    for (int j=0;j<4;j++){
      int lrow = wr*32 + mi*16 + (lane>>4)*4 + j;
      int row = r0 + lrow;
      #pragma unroll
      for (int ni=0; ni<2; ni++){
        int col = wc*32 + ni*16 + fr;
        if (row < M) C[(size_t)row*64 + col] = f2bf(acc[mi][ni][j]);
      }
      float s = acc[mi][0][j]*avs[0] + acc[mi][1][j]*avs[1];
      float d = acc[mi][0][j]*avd[0] + acc[mi][1][j]*avd[1];
      #pragma unroll
      for (int mk=1; mk<16; mk<<=1){
        s += __shfl_xor(s, mk); d += __shfl_xor(d, mk);
      }
      if ((lane & 15) == 0){ sS[wc][lrow] = s; sD[wc][lrow] = d; }
    }
  }
  __syncthreads();
  if (tid < 64){
    int row = r0 + tid;
    if (row < M){
      asrc[row] = sS[0][tid] + sS[1][tid];
      adst[row] = sD[0][tid] + sD[1][tid];
    }
  }
}

// ---------------- layer-1 aggregation: wave/node, 2 edges per load iter -----------
// lanes 0-31 handle even-offset edges, 32-63 odd; lane covers 8 channels (uint4).
// processes node range [i0, iend)  (split into 2 dispatches for profile visibility)
__global__ __launch_bounds__(256) void k_agg1(
    const unsigned short* __restrict__ h1, const float* __restrict__ asrc,
    const float* __restrict__ adst, const int* __restrict__ rowptr,
    const int* __restrict__ srcs, const unsigned short* __restrict__ p1,
    const float* __restrict__ bias, unsigned short* __restrict__ zb, int i0, int iend){
  int i = i0 + ((blockIdx.x*256 + threadIdx.x) >> 6);
  int lane = threadIdx.x & 63;
  if (i >= iend) return;
  int half = lane >> 5, l32 = lane & 31;
  int hd = l32 >> 2;                 // channels l32*8..+7, head = l32/4
  float acc[8] = {0.f,0.f,0.f,0.f,0.f,0.f,0.f,0.f};
  float ssum = 0.f;
  if (half == 0){
    float pself = __expf(lrelu(asrc[(size_t)i*8 + hd] + adst[(size_t)i*8 + hd]));
    uint4 hv = ((const uint4*)(h1 + (size_t)i*256))[l32];
    acc[0]=pself*b2f(hv.x&0xffff); acc[1]=pself*b2fh(hv.x);
    acc[2]=pself*b2f(hv.y&0xffff); acc[3]=pself*b2fh(hv.y);
    acc[4]=pself*b2f(hv.z&0xffff); acc[5]=pself*b2fh(hv.z);
    acc[6]=pself*b2f(hv.w&0xffff); acc[7]=pself*b2fh(hv.w);
    ssum = pself;
  }
  int e0 = rowptr[i], e1 = rowptr[i+1];
  int nume = e1 - e0;
  int full = nume & ~7;
  for (int eo = 0; eo < full; eo += 8){
    int sx[4]; float pv[4];
    #pragma unroll
    for (int j=0;j<4;j++){
      int e = e0 + eo + 2*j + half;
      sx[j] = srcs[e];
      pv[j] = b2f((unsigned)p1[(size_t)e*8 + hd]);
    }
    uint4 vv[4];
    #pragma unroll
    for (int j=0;j<4;j++) vv[j] = ((const uint4*)(h1 + (size_t)sx[j]*256))[l32];
    #pragma unroll
    for (int j=0;j<4;j++){
      float p = pv[j]; ssum += p;
      acc[0]+=p*b2f(vv[j].x&0xffff); acc[1]+=p*b2fh(vv[j].x);
      acc[2]+=p*b2f(vv[j].y&0xffff); acc[3]+=p*b2fh(vv[j].y);
      acc[4]+=p*b2f(vv[j].z&0xffff); acc[5]+=p*b2fh(vv[j].z);
      acc[6]+=p*b2f(vv[j].w&0xffff); acc[7]+=p*b2fh(vv[j].w);
    }
  }
  for (int eo = full; eo < nume; eo += 2){
    int idx = eo + half;
    bool ok = idx < nume;
    int e = e0 + (ok ? idx : 0);
    float p = ok ? b2f((unsigned)p1[(size_t)e*8 + hd]) : 0.f;
    uint4 v = ((const uint4*)(h1 + (size_t)srcs[e]*256))[l32];
    ssum += p;
    acc[0]+=p*b2f(v.x&0xffff); acc[1]+=p*b2fh(v.x);
    acc[2]+=p*b2f(v.y&0xffff); acc[3]+=p*b2fh(v.y);
    acc[4]+=p*b2f(v.z&0xffff); acc[5]+=p*b2fh(v.z);
    acc[6]+=p*b2f(v.w&0xffff); acc[7]+=p*b2fh(v.w);
  }
  ssum += __shfl_xor(ssum, 32);
  #pragma unroll
  for (int c=0;c<8;c++) acc[c] += __shfl_xor(acc[c], 32);
  if (half == 0){
    float inv = 1.f / ssum;
    float4 b0 = ((const float4*)bias)[l32*2];
    float4 b1 = ((const float4*)bias)[l32*2 + 1];
    unsigned short o0 = f2bf(fmaxf(fmaf(acc[0], inv, b0.x), 0.f));
    unsigned short o1 = f2bf(fmaxf(fmaf(acc[1], inv, b0.y), 0.f));
    unsigned short o2 = f2bf(fmaxf(fmaf(acc[2], inv, b0.z), 0.f));
    unsigned short o3 = f2bf(fmaxf(fmaf(acc[3], inv, b0.w), 0.f));
    unsigned short o4 = f2bf(fmaxf(fmaf(acc[4], inv, b1.x), 0.f));
    unsigned short o5 = f2bf(fmaxf(fmaf(acc[5], inv, b1.y), 0.f));
    unsigned short o6 = f2bf(fmaxf(fmaf(acc[6], inv, b1.z), 0.f));
    unsigned short o7 = f2bf(fmaxf(fmaf(acc[7], inv, b1.w), 0.f));
    uint4 ov;
    ov.x = (unsigned)o0 | ((unsigned)o1 << 16);
    ov.y = (unsigned)o2 | ((unsigned)o3 << 16);
    ov.z = (unsigned)o4 | ((unsigned)o5 << 16);
    ov.w = (unsigned)o6 | ((unsigned)o7 << 16);
    ((uint4*)(zb + (size_t)i*256))[l32] = ov;
  }
}

// ---------------- layer-2 aggregation + log_softmax, 4 edges/half per iter --------
__global__ __launch_bounds__(256) void k_agg2(
    const unsigned short* __restrict__ h2, const float* __restrict__ asrc,
    const float* __restrict__ adst, const int* __restrict__ rowptr,
    const int* __restrict__ srcs, const float* __restrict__ p2,
    const float* __restrict__ bias, float* __restrict__ out, int n){
  int i = (blockIdx.x*256 + threadIdx.x) >> 6;
  int lane = threadIdx.x & 63;
  if (i >= n) return;
  int half = lane >> 5, l32 = lane & 31;
  int c0 = l32*2;
  bool act = l32 < 20;               // cols c0, c0+1 < 40
  float acc0 = 0.f, acc1 = 0.f, ssum = 0.f;
  if (half == 0){
    float pself = __expf(lrelu(asrc[i] + adst[i]));
    unsigned hv = ((const unsigned*)(h2 + (size_t)i*64))[l32];
    acc0 = pself * b2f(hv & 0xffff);
    acc1 = pself * b2fh(hv);
    ssum = pself;
  }
  int e0 = rowptr[i], e1 = rowptr[i+1];
  int nume = e1 - e0;
  int full = nume & ~15;
  for (int eo = 0; eo < full; eo += 16){
    int sx[8]; float pv[8];
    #pragma unroll
    for (int j=0;j<8;j++){
      int e = e0 + eo + 2*j + half;
      sx[j] = srcs[e];
      pv[j] = p2[e];
    }
    unsigned vv[8];
    #pragma unroll
    for (int j=0;j<8;j++) vv[j] = ((const unsigned*)(h2 + (size_t)sx[j]*64))[l32];
    #pragma unroll
    for (int j=0;j<8;j++){
      float p = pv[j]; ssum += p;
      acc0 += p * b2f(vv[j] & 0xffff);
      acc1 += p * b2fh(vv[j]);
    }
  }
  for (int eo = full; eo < nume; eo += 2){
    int idx = eo + half;
    bool ok = idx < nume;
    int e = e0 + (ok ? idx : 0);
    float p = ok ? p2[e] : 0.f;
    unsigned v = ((const unsigned*)(h2 + (size_t)srcs[e]*64))[l32];
    ssum += p;
    acc0 += p * b2f(v & 0xffff);
    acc1 += p * b2fh(v);
  }
  ssum += __shfl_xor(ssum, 32);
  acc0 += __shfl_xor(acc0, 32);
  acc1 += __shfl_xor(acc1, 32);
  float inv = 1.f / ssum;
  float v0 = act ? (acc0*inv + bias[c0])   : -INFINITY;
  float v1 = act ? (acc1*inv + bias[c0+1]) : -INFINITY;
  float mx = fmaxf(v0, v1);
  #pragma unroll
  for (int off=32; off; off>>=1) mx = fmaxf(mx, __shfl_xor(mx, off));
  float ex = (half == 0 && act) ? (__expf(v0 - mx) + __expf(v1 - mx)) : 0.f;
  #pragma unroll
  for (int off=32; off; off>>=1) ex += __shfl_xor(ex, off);
  if (half == 0 && act){
    float ls = __logf(ex);
    float2 o; o.x = v0 - mx - ls; o.y = v1 - mx - ls;
    ((float2*)(out + (size_t)i*40))[l32] = o;
  }
}

extern "C" void kernel_launch(void* const* d_in, const int* in_sizes, int n_in,
                              void* d_out, int out_size, void* d_ws, size_t ws_size,
                              hipStream_t stream){
  const float* x   = (const float*)d_in[0];
  const int*   ei  = (const int*)d_in[1];
  const float* W1  = (const float*)d_in[2];
  const float* as1 = (const float*)d_in[3];
  const float* ad1 = (const float*)d_in[4];
  const float* b1  = (const float*)d_in[5];
  const float* W2  = (const float*)d_in[6];
  const float* as2 = (const float*)d_in[7];
  const float* ad2 = (const float*)d_in[8];
  const float* b2  = (const float*)d_in[9];
  float* out = (float*)d_out;

  const int N = in_sizes[0] / 128;
  const int E = in_sizes[1] / 2;
  const int* srcI = ei;
  const int* dstI = ei + E;

  char* ws = (char*)d_ws;
  size_t off = 0;
  auto alloc = [&](size_t bytes){ void* p = ws + off; off += (bytes + 255) & ~(size_t)255; return p; };
  unsigned short* h1b = (unsigned short*)alloc((size_t)N*256*2);
  unsigned short* zb  = (unsigned short*)alloc((size_t)N*256*2);
  unsigned short* h2b = (unsigned short*)alloc((size_t)N*64*2);
  unsigned short* W1t = (unsigned short*)alloc((size_t)256*128*2);
  unsigned short* W2t = (unsigned short*)alloc((size_t)64*256*2);
  unsigned short* p1  = (unsigned short*)alloc((size_t)E*8*2);
  float* p2    = (float*)alloc((size_t)E*4);
  float* asrc1 = (float*)alloc((size_t)N*8*4);
  float* adst1 = (float*)alloc((size_t)N*8*4);
  float* asrc2 = (float*)alloc((size_t)N*4);
  float* adst2 = (float*)alloc((size_t)N*4);
  int* deg     = (int*)alloc((size_t)N*4);
  int* rowptr  = (int*)alloc((size_t)(N+1)*4);
  int* nxt     = (int*)alloc((size_t)N*4);
  int* srcs    = (int*)alloc((size_t)E*4);
  int* bsum    = (int*)alloc(256*4);
  (void)ws_size; (void)n_in; (void)out_size;

  const int nb = (N + 1023)/1024;
  const int eb = (E + 255)/256;
  hipMemsetAsync(deg, 0, (size_t)N*4, stream);
  k_count_wt<<<eb + 192, 256, 0, stream>>>(dstI, deg, E, eb, W1, W1t, W2, W2t);
  k_scan1 <<<nb, 256, 0, stream>>>(deg, bsum, N);
  k_scan3 <<<nb, 256, 0, stream>>>(deg, bsum, rowptr, nxt, N, nb);
  k_scatter<<<eb, 256, 0, stream>>>(srcI, dstI, nxt, srcs, E);

  // layer 1
  gemm1_att<<<(N + 63)/64, 256, 0, stream>>>(x, W1t, h1b, as1, ad1, asrc1, adst1, N);
  k_edgep1n<<<(N + 3)/4, 256, 0, stream>>>(rowptr, srcs, asrc1, adst1, p1, N);
  int half = N/2;
  k_agg1<<<(half + 3)/4, 256, 0, stream>>>(h1b, asrc1, adst1, rowptr, srcs, p1, b1, zb, 0, half);
  k_agg1<<<((N - half) + 3)/4, 256, 0, stream>>>(h1b, asrc1, adst1, rowptr, srcs, p1, b1, zb, half, N);

  // layer 2
  gemm2_att<<<(N + 63)/64, 256, 0, stream>>>(zb, W2t, h2b, as2, ad2, asrc2, adst2, N);
  k_edgep2n<<<(N + 3)/4, 256, 0, stream>>>(rowptr, srcs, asrc2, adst2, p2, N);
  k_agg2<<<(N + 3)/4, 256, 0, stream>>>(h2b, asrc2, adst2, rowptr, srcs, p2, b2, out, N);
}

// Round 12
// 300.117 us; speedup vs baseline: 1.1692x; 1.1692x over previous
//
#include <hip/hip_runtime.h>
#include <hip/hip_bf16.h>
#include <math.h>

#define NEG_SLOPE 0.2f

__device__ __forceinline__ float lrelu(float x){ return x > 0.f ? x : NEG_SLOPE * x; }
__device__ __forceinline__ unsigned short f2bf(float f){
  __hip_bfloat16 h = __float2bfloat16(f);
  return __builtin_bit_cast(unsigned short, h);
}
__device__ __forceinline__ float b2f(unsigned u){
  return __builtin_bit_cast(float, u << 16);
}
__device__ __forceinline__ float b2fh(unsigned u){
  return __builtin_bit_cast(float, u & 0xffff0000u);
}

typedef short bf16x8 __attribute__((ext_vector_type(8)));
typedef float f32x4 __attribute__((ext_vector_type(4)));

// ---------------- CSR count (records per-edge rank) + weight transpose ----------------
__global__ void k_count_wt(const int* __restrict__ dst, int* __restrict__ deg,
                           int* __restrict__ rank, int E, int eb,
                           const float* __restrict__ W1, unsigned short* __restrict__ W1t,
                           const float* __restrict__ W2, unsigned short* __restrict__ W2t){
  int b = blockIdx.x, tid = threadIdx.x;
  if (b < eb){
    int e = b*256 + tid;
    if (e < E) rank[e] = atomicAdd(&deg[dst[e]], 1);
  } else {
    int bb = b - eb;
    if (bb < 128){                    // W1: 256 cols, K=128; 2 cols per block
      int c = bb*2 + (tid>>7), k = tid & 127;
      W1t[(size_t)c*128 + k] = f2bf(W1[(size_t)k*256 + c]);
    } else {                          // W2: 64 cols (pad>=40 -> 0), K=256
      int c = bb - 128, k = tid;
      float v = (c < 40) ? W2[(size_t)k*40 + c] : 0.f;
      W2t[(size_t)c*256 + k] = f2bf(v);
    }
  }
}

__global__ __launch_bounds__(256) void k_scan1(const int* __restrict__ deg, int* __restrict__ bsum, int n){
  int tid = threadIdx.x;
  int base = blockIdx.x*1024 + tid*4;
  int s = 0;
  #pragma unroll
  for (int j=0;j<4;j++){ int idx = base+j; if (idx < n) s += deg[idx]; }
  #pragma unroll
  for (int off=32; off; off>>=1) s += __shfl_xor(s, off);
  __shared__ int ws[4];
  if ((tid&63)==0) ws[tid>>6] = s;
  __syncthreads();
  if (tid==0) bsum[blockIdx.x] = ws[0]+ws[1]+ws[2]+ws[3];
}

// local scan + inline block-offset scan (nb <= 64)
__global__ __launch_bounds__(256) void k_scan3(const int* __restrict__ deg, const int* __restrict__ bsum,
    int* __restrict__ rowptr, int n, int nb){
  int tid = threadIdx.x; int lane = tid & 63, w = tid >> 6;
  __shared__ int ws[4];
  __shared__ int s_boff;
  if (tid < 64){
    int v = (lane < nb) ? bsum[lane] : 0;
    int inc = v;
    #pragma unroll
    for (int off=1; off<64; off<<=1){ int t = __shfl_up(inc, off); if (lane >= off) inc += t; }
    if (lane == blockIdx.x) s_boff = inc - v;
    if (blockIdx.x == 0 && lane == nb-1) rowptr[n] = inc;
  }
  __syncthreads();
  int base = blockIdx.x*1024 + tid*4;
  int v[4]; int s = 0;
  #pragma unroll
  for (int j=0;j<4;j++){ int idx = base+j; v[j] = (idx < n) ? deg[idx] : 0; s += v[j]; }
  int inc = s;
  #pragma unroll
  for (int off=1; off<64; off<<=1){ int t = __shfl_up(inc, off); if (lane >= off) inc += t; }
  if (lane == 63) ws[w] = inc;
  __syncthreads();
  int run = s_boff;
  for (int ww=0; ww<w; ww++) run += ws[ww];
  run += inc - s;
  #pragma unroll
  for (int j=0;j<4;j++){ int idx = base+j; if (idx < n) rowptr[idx] = run, run += v[j]; }
}

// atomic-free scatter: pos = rowptr[dst] + rank
__global__ void k_scatter(const int* __restrict__ src, const int* __restrict__ dst,
                          const int* __restrict__ rowptr, const int* __restrict__ rank,
                          int* __restrict__ srcs, int E){
  int e = blockIdx.x*256 + threadIdx.x;
  if (e < E){
    srcs[rowptr[dst[e]] + rank[e]] = src[e];
  }
}

// ---------------- edge p precompute (per-node waves; dst implicit) ----------------
__global__ __launch_bounds__(256) void k_edgep1n(const int* __restrict__ rowptr,
    const int* __restrict__ srcs, const float* __restrict__ asrc,
    const float* __restrict__ adst, unsigned short* __restrict__ p1, int n){
  int i = (blockIdx.x*256 + threadIdx.x) >> 6;
  int lane = threadIdx.x & 63;
  if (i >= n) return;
  int hd = lane & 7, eoff = lane >> 3;
  float ad = adst[(size_t)i*8 + hd];
  int e0 = rowptr[i], e1 = rowptr[i+1];
  for (int e = e0 + eoff; e < e1; e += 8){
    int s = srcs[e];
    p1[(size_t)e*8 + hd] = f2bf(__expf(lrelu(asrc[(size_t)s*8 + hd] + ad)));
  }
}

__global__ __launch_bounds__(256) void k_edgep2n(const int* __restrict__ rowptr,
    const int* __restrict__ srcs, const float* __restrict__ asrc,
    const float* __restrict__ adst, float* __restrict__ p2, int n){
  int i = (blockIdx.x*256 + threadIdx.x) >> 6;
  int lane = threadIdx.x & 63;
  if (i >= n) return;
  float ad = adst[i];
  int e0 = rowptr[i], e1 = rowptr[i+1];
  for (int e = e0 + lane; e < e1; e += 64){
    p2[e] = __expf(lrelu(asrc[srcs[e]] + ad));
  }
}

// ---------------- layer-1 GEMM (fp32 A staged->bf16) + fused attention dots ------
__global__ __launch_bounds__(256) void gemm1_att(
    const float* __restrict__ x, const unsigned short* __restrict__ Bt,
    unsigned short* __restrict__ C, const float* __restrict__ att_s,
    const float* __restrict__ att_d, float* __restrict__ asrc,
    float* __restrict__ adst, int M){
  __shared__ unsigned short sA[64][40];
  __shared__ unsigned short sB[256][40];
  const int tid = threadIdx.x;
  const int wid = tid >> 6, lane = tid & 63;
  const int r0 = blockIdx.x * 64;
  const int fr = lane & 15, fk = (lane >> 4) * 8;
  f32x4 acc[4][4] = {};

  for (int k0 = 0; k0 < 128; k0 += 32){
    #pragma unroll
    for (int t=0; t<2; t++){
      int id = tid + t*256;          // 0..511
      int r = id >> 3, q = id & 7;   // row, k-quad
      float4 v = make_float4(0.f,0.f,0.f,0.f);
      int row = r0 + r;
      if (row < M) v = ((const float4*)(x + (size_t)row*128))[(k0>>2) + q];
      ushort4 o; o.x=f2bf(v.x); o.y=f2bf(v.y); o.z=f2bf(v.z); o.w=f2bf(v.w);
      *(ushort4*)&sA[r][q*4] = o;
    }
    #pragma unroll
    for (int t=0; t<4; t++){
      int id = tid + t*256;          // 0..1023
      int r = id >> 2, lk = (id & 3) * 8;
      uint4 vb = *(const uint4*)(Bt + (size_t)r*128 + k0 + lk);
      *(uint4*)&sB[r][lk] = vb;
    }
    __syncthreads();
    bf16x8 a[4], b[4];
    #pragma unroll
    for (int mi=0; mi<4; mi++) a[mi] = *(const bf16x8*)&sA[mi*16 + fr][fk];
    #pragma unroll
    for (int ni=0; ni<4; ni++) b[ni] = *(const bf16x8*)&sB[wid*64 + ni*16 + fr][fk];
    #pragma unroll
    for (int mi=0; mi<4; mi++)
      #pragma unroll
      for (int ni=0; ni<4; ni++)
        acc[mi][ni] = __builtin_amdgcn_mfma_f32_16x16x32_bf16(a[mi], b[ni], acc[mi][ni], 0,0,0);
    __syncthreads();
  }

  float avs[4], avd[4];
  #pragma unroll
  for (int ni=0; ni<4; ni++){
    int idx = (2*wid + (ni>>1))*32 + (ni&1)*16 + fr;
    avs[ni] = att_s[idx];
    avd[ni] = att_d[idx];
  }

  #pragma unroll
  for (int mi=0; mi<4; mi++){
    #pragma unroll
    for (int j=0; j<4; j++){
      int row = r0 + mi*16 + (lane>>4)*4 + j;
      #pragma unroll
      for (int ni=0; ni<4; ni++){
        int col = wid*64 + ni*16 + fr;
        if (row < M) C[(size_t)row*256 + col] = f2bf(acc[mi][ni][j]);
      }
      float s0 = acc[mi][0][j]*avs[0] + acc[mi][1][j]*avs[1];
      float s1 = acc[mi][2][j]*avs[2] + acc[mi][3][j]*avs[3];
      float d0 = acc[mi][0][j]*avd[0] + acc[mi][1][j]*avd[1];
      float d1 = acc[mi][2][j]*avd[2] + acc[mi][3][j]*avd[3];
      #pragma unroll
      for (int mk=1; mk<16; mk<<=1){
        s0 += __shfl_xor(s0, mk); s1 += __shfl_xor(s1, mk);
        d0 += __shfl_xor(d0, mk); d1 += __shfl_xor(d1, mk);
      }
      if ((lane & 15) == 0 && row < M){
        asrc[(size_t)row*8 + 2*wid    ] = s0;
        asrc[(size_t)row*8 + 2*wid + 1] = s1;
        adst[(size_t)row*8 + 2*wid    ] = d0;
        adst[(size_t)row*8 + 2*wid + 1] = d1;
      }
    }
  }
}

// ---------------- layer-2 GEMM + fused attention dots ----------------
__global__ __launch_bounds__(256) void gemm2_att(
    const unsigned short* __restrict__ A, const unsigned short* __restrict__ Bt,
    unsigned short* __restrict__ C, const float* __restrict__ att_s,
    const float* __restrict__ att_d, float* __restrict__ asrc,
    float* __restrict__ adst, int M){
  __shared__ unsigned short sA[64][40];
  __shared__ unsigned short sB[64][40];
  __shared__ float sS[2][64], sD[2][64];
  const int tid = threadIdx.x;
  const int wid = tid >> 6, lane = tid & 63;
  const int r0 = blockIdx.x * 64;
  const int wr = wid >> 1, wc = wid & 1;
  const int lr = tid >> 2;
  const int lk = (tid & 3) * 8;
  const int fr = lane & 15, fk = (lane >> 4) * 8;
  const int K = 256;
  f32x4 acc[2][2] = {};

  for (int k0 = 0; k0 < K; k0 += 32){
    uint4 va = make_uint4(0,0,0,0);
    int row = r0 + lr;
    if (row < M) va = *(const uint4*)(A + (size_t)row*K + k0 + lk);
    *(uint4*)&sA[lr][lk] = va;
    uint4 vb = *(const uint4*)(Bt + (size_t)lr*K + k0 + lk);
    *(uint4*)&sB[lr][lk] = vb;
    __syncthreads();
    bf16x8 a0 = *(const bf16x8*)&sA[wr*32 + fr][fk];
    bf16x8 a1 = *(const bf16x8*)&sA[wr*32 + 16 + fr][fk];
    bf16x8 b0 = *(const bf16x8*)&sB[wc*32 + fr][fk];
    bf16x8 b1 = *(const bf16x8*)&sB[wc*32 + 16 + fr][fk];
    acc[0][0] = __builtin_amdgcn_mfma_f32_16x16x32_bf16(a0, b0, acc[0][0], 0,0,0);
    acc[0][1] = __builtin_amdgcn_mfma_f32_16x16x32_bf16(a0, b1, acc[0][1], 0,0,0);
    acc[1][0] = __builtin_amdgcn_mfma_f32_16x16x32_bf16(a1, b0, acc[1][0], 0,0,0);
    acc[1][1] = __builtin_amdgcn_mfma_f32_16x16x32_bf16(a1, b1, acc[1][1], 0,0,0);
    __syncthreads();
  }

  float avs[2], avd[2];
  #pragma unroll
  for (int ni=0; ni<2; ni++){
    int col = wc*32 + ni*16 + fr;
    avs[ni] = (col < 40) ? att_s[col] : 0.f;
    avd[ni] = (col < 40) ? att_d[col] : 0.f;
  }

  #pragma unroll
  for (int mi=0; mi<2; mi++){
    #pragma unroll
    for (int j=0;j<4;j++){
      int lrow = wr*32 + mi*16 + (lane>>4)*4 + j;
      int row = r0 + lrow;
      #pragma unroll
      for (int ni=0; ni<2; ni++){
        int col = wc*32 + ni*16 + fr;
        if (row < M) C[(size_t)row*64 + col] = f2bf(acc[mi][ni][j]);
      }
      float s = acc[mi][0][j]*avs[0] + acc[mi][1][j]*avs[1];
      float d = acc[mi][0][j]*avd[0] + acc[mi][1][j]*avd[1];
      #pragma unroll
      for (int mk=1; mk<16; mk<<=1){
        s += __shfl_xor(s, mk); d += __shfl_xor(d, mk);
      }
      if ((lane & 15) == 0){ sS[wc][lrow] = s; sD[wc][lrow] = d; }
    }
  }
  __syncthreads();
  if (tid < 64){
    int row = r0 + tid;
    if (row < M){
      asrc[row] = sS[0][tid] + sS[1][tid];
      adst[row] = sD[0][tid] + sD[1][tid];
    }
  }
}

// ---------------- layer-1 aggregation: wave/node, 2 edges per load iter -----------
__global__ __launch_bounds__(256) void k_agg1(
    const unsigned short* __restrict__ h1, const float* __restrict__ asrc,
    const float* __restrict__ adst, const int* __restrict__ rowptr,
    const int* __restrict__ srcs, const unsigned short* __restrict__ p1,
    const float* __restrict__ bias, unsigned short* __restrict__ zb, int n){
  int i = (blockIdx.x*256 + threadIdx.x) >> 6;
  int lane = threadIdx.x & 63;
  if (i >= n) return;
  int half = lane >> 5, l32 = lane & 31;
  int hd = l32 >> 2;                 // channels l32*8..+7, head = l32/4
  float acc[8] = {0.f,0.f,0.f,0.f,0.f,0.f,0.f,0.f};
  float ssum = 0.f;
  if (half == 0){
    float pself = __expf(lrelu(asrc[(size_t)i*8 + hd] + adst[(size_t)i*8 + hd]));
    uint4 hv = ((const uint4*)(h1 + (size_t)i*256))[l32];
    acc[0]=pself*b2f(hv.x&0xffff); acc[1]=pself*b2fh(hv.x);
    acc[2]=pself*b2f(hv.y&0xffff); acc[3]=pself*b2fh(hv.y);
    acc[4]=pself*b2f(hv.z&0xffff); acc[5]=pself*b2fh(hv.z);
    acc[6]=pself*b2f(hv.w&0xffff); acc[7]=pself*b2fh(hv.w);
    ssum = pself;
  }
  int e0 = rowptr[i], e1 = rowptr[i+1];
  int nume = e1 - e0;
  int full = nume & ~7;
  for (int eo = 0; eo < full; eo += 8){
    int sx[4]; float pv[4];
    #pragma unroll
    for (int j=0;j<4;j++){
      int e = e0 + eo + 2*j + half;
      sx[j] = srcs[e];
      pv[j] = b2f((unsigned)p1[(size_t)e*8 + hd]);
    }
    uint4 vv[4];
    #pragma unroll
    for (int j=0;j<4;j++) vv[j] = ((const uint4*)(h1 + (size_t)sx[j]*256))[l32];
    #pragma unroll
    for (int j=0;j<4;j++){
      float p = pv[j]; ssum += p;
      acc[0]+=p*b2f(vv[j].x&0xffff); acc[1]+=p*b2fh(vv[j].x);
      acc[2]+=p*b2f(vv[j].y&0xffff); acc[3]+=p*b2fh(vv[j].y);
      acc[4]+=p*b2f(vv[j].z&0xffff); acc[5]+=p*b2fh(vv[j].z);
      acc[6]+=p*b2f(vv[j].w&0xffff); acc[7]+=p*b2fh(vv[j].w);
    }
  }
  for (int eo = full; eo < nume; eo += 2){
    int idx = eo + half;
    bool ok = idx < nume;
    int e = e0 + (ok ? idx : 0);
    float p = ok ? b2f((unsigned)p1[(size_t)e*8 + hd]) : 0.f;
    uint4 v = ((const uint4*)(h1 + (size_t)srcs[e]*256))[l32];
    ssum += p;
    acc[0]+=p*b2f(v.x&0xffff); acc[1]+=p*b2fh(v.x);
    acc[2]+=p*b2f(v.y&0xffff); acc[3]+=p*b2fh(v.y);
    acc[4]+=p*b2f(v.z&0xffff); acc[5]+=p*b2fh(v.z);
    acc[6]+=p*b2f(v.w&0xffff); acc[7]+=p*b2fh(v.w);
  }
  ssum += __shfl_xor(ssum, 32);
  #pragma unroll
  for (int c=0;c<8;c++) acc[c] += __shfl_xor(acc[c], 32);
  if (half == 0){
    float inv = 1.f / ssum;
    float4 b0 = ((const float4*)bias)[l32*2];
    float4 b1 = ((const float4*)bias)[l32*2 + 1];
    unsigned short o0 = f2bf(fmaxf(fmaf(acc[0], inv, b0.x), 0.f));
    unsigned short o1 = f2bf(fmaxf(fmaf(acc[1], inv, b0.y), 0.f));
    unsigned short o2 = f2bf(fmaxf(fmaf(acc[2], inv, b0.z), 0.f));
    unsigned short o3 = f2bf(fmaxf(fmaf(acc[3], inv, b0.w), 0.f));
    unsigned short o4 = f2bf(fmaxf(fmaf(acc[4], inv, b1.x), 0.f));
    unsigned short o5 = f2bf(fmaxf(fmaf(acc[5], inv, b1.y), 0.f));
    unsigned short o6 = f2bf(fmaxf(fmaf(acc[6], inv, b1.z), 0.f));
    unsigned short o7 = f2bf(fmaxf(fmaf(acc[7], inv, b1.w), 0.f));
    uint4 ov;
    ov.x = (unsigned)o0 | ((unsigned)o1 << 16);
    ov.y = (unsigned)o2 | ((unsigned)o3 << 16);
    ov.z = (unsigned)o4 | ((unsigned)o5 << 16);
    ov.w = (unsigned)o6 | ((unsigned)o7 << 16);
    ((uint4*)(zb + (size_t)i*256))[l32] = ov;
  }
}

// ---------------- layer-2 aggregation + log_softmax, 2 edges per load iter --------
__global__ __launch_bounds__(256) void k_agg2(
    const unsigned short* __restrict__ h2, const float* __restrict__ asrc,
    const float* __restrict__ adst, const int* __restrict__ rowptr,
    const int* __restrict__ srcs, const float* __restrict__ p2,
    const float* __restrict__ bias, float* __restrict__ out, int n){
  int i = (blockIdx.x*256 + threadIdx.x) >> 6;
  int lane = threadIdx.x & 63;
  if (i >= n) return;
  int half = lane >> 5, l32 = lane & 31;
  int c0 = l32*2;
  bool act = l32 < 20;               // cols c0, c0+1 < 40
  float acc0 = 0.f, acc1 = 0.f, ssum = 0.f;
  if (half == 0){
    float pself = __expf(lrelu(asrc[i] + adst[i]));
    unsigned hv = ((const unsigned*)(h2 + (size_t)i*64))[l32];
    acc0 = pself * b2f(hv & 0xffff);
    acc1 = pself * b2fh(hv);
    ssum = pself;
  }
  int e0 = rowptr[i], e1 = rowptr[i+1];
  int nume = e1 - e0;
  int full = nume & ~7;
  for (int eo = 0; eo < full; eo += 8){
    int sx[4]; float pv[4];
    #pragma unroll
    for (int j=0;j<4;j++){
      int e = e0 + eo + 2*j + half;
      sx[j] = srcs[e];
      pv[j] = p2[e];
    }
    unsigned vv[4];
    #pragma unroll
    for (int j=0;j<4;j++) vv[j] = ((const unsigned*)(h2 + (size_t)sx[j]*64))[l32];
    #pragma unroll
    for (int j=0;j<4;j++){
      float p = pv[j]; ssum += p;
      acc0 += p * b2f(vv[j] & 0xffff);
      acc1 += p * b2fh(vv[j]);
    }
  }
  for (int eo = full; eo < nume; eo += 2){
    int idx = eo + half;
    bool ok = idx < nume;
    int e = e0 + (ok ? idx : 0);
    float p = ok ? p2[e] : 0.f;
    unsigned v = ((const unsigned*)(h2 + (size_t)srcs[e]*64))[l32];
    ssum += p;
    acc0 += p * b2f(v & 0xffff);
    acc1 += p * b2fh(v);
  }
  ssum += __shfl_xor(ssum, 32);
  acc0 += __shfl_xor(acc0, 32);
  acc1 += __shfl_xor(acc1, 32);
  float inv = 1.f / ssum;
  float v0 = act ? (acc0*inv + bias[c0])   : -INFINITY;
  float v1 = act ? (acc1*inv + bias[c0+1]) : -INFINITY;
  float mx = fmaxf(v0, v1);
  #pragma unroll
  for (int off=32; off; off>>=1) mx = fmaxf(mx, __shfl_xor(mx, off));
  float ex = (half == 0 && act) ? (__expf(v0 - mx) + __expf(v1 - mx)) : 0.f;
  #pragma unroll
  for (int off=32; off; off>>=1) ex += __shfl_xor(ex, off);
  if (half == 0 && act){
    float ls = __logf(ex);
    float2 o; o.x = v0 - mx - ls; o.y = v1 - mx - ls;
    ((float2*)(out + (size_t)i*40))[l32] = o;
  }
}

extern "C" void kernel_launch(void* const* d_in, const int* in_sizes, int n_in,
                              void* d_out, int out_size, void* d_ws, size_t ws_size,
                              hipStream_t stream){
  const float* x   = (const float*)d_in[0];
  const int*   ei  = (const int*)d_in[1];
  const float* W1  = (const float*)d_in[2];
  const float* as1 = (const float*)d_in[3];
  const float* ad1 = (const float*)d_in[4];
  const float* b1  = (const float*)d_in[5];
  const float* W2  = (const float*)d_in[6];
  const float* as2 = (const float*)d_in[7];
  const float* ad2 = (const float*)d_in[8];
  const float* b2  = (const float*)d_in[9];
  float* out = (float*)d_out;

  const int N = in_sizes[0] / 128;
  const int E = in_sizes[1] / 2;
  const int* srcI = ei;
  const int* dstI = ei + E;

  char* ws = (char*)d_ws;
  size_t off = 0;
  auto alloc = [&](size_t bytes){ void* p = ws + off; off += (bytes + 255) & ~(size_t)255; return p; };
  unsigned short* h1b = (unsigned short*)alloc((size_t)N*256*2);
  unsigned short* zb  = (unsigned short*)alloc((size_t)N*256*2);
  unsigned short* h2b = (unsigned short*)alloc((size_t)N*64*2);
  unsigned short* W1t = (unsigned short*)alloc((size_t)256*128*2);
  unsigned short* W2t = (unsigned short*)alloc((size_t)64*256*2);
  unsigned short* p1  = (unsigned short*)alloc((size_t)E*8*2);
  float* p2    = (float*)alloc((size_t)E*4);
  float* asrc1 = (float*)alloc((size_t)N*8*4);
  float* adst1 = (float*)alloc((size_t)N*8*4);
  float* asrc2 = (float*)alloc((size_t)N*4);
  float* adst2 = (float*)alloc((size_t)N*4);
  int* deg     = (int*)alloc((size_t)N*4);
  int* rowptr  = (int*)alloc((size_t)(N+1)*4);
  int* rank    = (int*)alloc((size_t)E*4);
  int* srcs    = (int*)alloc((size_t)E*4);
  int* bsum    = (int*)alloc(256*4);
  (void)ws_size; (void)n_in; (void)out_size;

  const int nb = (N + 1023)/1024;
  const int eb = (E + 255)/256;
  hipMemsetAsync(deg, 0, (size_t)N*4, stream);
  k_count_wt<<<eb + 192, 256, 0, stream>>>(dstI, deg, rank, E, eb, W1, W1t, W2, W2t);
  k_scan1 <<<nb, 256, 0, stream>>>(deg, bsum, N);
  k_scan3 <<<nb, 256, 0, stream>>>(deg, bsum, rowptr, N, nb);
  k_scatter<<<eb, 256, 0, stream>>>(srcI, dstI, rowptr, rank, srcs, E);

  // layer 1
  gemm1_att<<<(N + 63)/64, 256, 0, stream>>>(x, W1t, h1b, as1, ad1, asrc1, adst1, N);
  k_edgep1n<<<(N + 3)/4, 256, 0, stream>>>(rowptr, srcs, asrc1, adst1, p1, N);
  k_agg1<<<(N + 3)/4, 256, 0, stream>>>(h1b, asrc1, adst1, rowptr, srcs, p1, b1, zb, N);

  // layer 2
  gemm2_att<<<(N + 63)/64, 256, 0, stream>>>(zb, W2t, h2b, as2, ad2, asrc2, adst2, N);
  k_edgep2n<<<(N + 3)/4, 256, 0, stream>>>(rowptr, srcs, asrc2, adst2, p2, N);
  k_agg2<<<(N + 3)/4, 256, 0, stream>>>(h2b, asrc2, adst2, rowptr, srcs, p2, b2, out, N);
}